// Round 1
// baseline (200.218 us; speedup 1.0000x reference)
//
#include <hip/hip_runtime.h>

#define ALPHA 0.2f
#define BATCH 8
#define NN    2048
#define FD    256

typedef __attribute__((ext_vector_type(8))) short short8;
typedef __attribute__((ext_vector_type(4))) float f32x4;

__device__ __forceinline__ unsigned short f2bf(float f){
  unsigned u = __builtin_bit_cast(unsigned, f);
  return (unsigned short)((u + 0x7FFFu + ((u>>16)&1u)) >> 16);   // RTN-even
}
__device__ __forceinline__ float bf2f(unsigned short h){
  return __builtin_bit_cast(float, ((unsigned)h)<<16);
}
__device__ __forceinline__ float dot4(float4 a, float4 b){
  return a.x*b.x + a.y*b.y + a.z*b.z + a.w*b.w;
}

// ---------------------------------------------------------------------------
// K0: w_src = W @ a_src, w_dst = W @ a_dst  (exact fp32),  WT[o][k] = bf16(W[k][o])
// one 64-lane block per k-row of W
// ---------------------------------------------------------------------------
__global__ __launch_bounds__(64) void prep_w(
    const float* __restrict__ W, const float* __restrict__ a,
    float* __restrict__ w_src, float* __restrict__ w_dst,
    unsigned short* __restrict__ WT)
{
  const int k = blockIdx.x;
  const int l = threadIdx.x;
  float4 wv = *(const float4*)(W + k*FD + l*4);
  float4 as = *(const float4*)(a + l*4);
  float4 ad = *(const float4*)(a + FD + l*4);
  float s = dot4(wv, as);
  float d = dot4(wv, ad);
#pragma unroll
  for (int m=1;m<64;m<<=1){ s += __shfl_xor(s, m); d += __shfl_xor(d, m); }
  if (l == 0){ w_src[k] = s; w_dst[k] = d; }
  WT[(l*4+0)*FD + k] = f2bf(wv.x);
  WT[(l*4+1)*FD + k] = f2bf(wv.y);
  WT[(l*4+2)*FD + k] = f2bf(wv.z);
  WT[(l*4+3)*FD + k] = f2bf(wv.w);
}

// ---------------------------------------------------------------------------
// K0b: e_src[row] = x[row]·w_src, e_dst[row] = x[row]·w_dst (exact fp32)
//      xb = bf16(x).  One wave per row, 4 rows per 256-thread block.
// ---------------------------------------------------------------------------
__global__ __launch_bounds__(256) void prep_x(
    const float* __restrict__ x,
    const float* __restrict__ w_src, const float* __restrict__ w_dst,
    unsigned short* __restrict__ xb,
    float* __restrict__ e_src, float* __restrict__ e_dst)
{
  const int row = blockIdx.x*4 + (threadIdx.x >> 6);
  const int l = threadIdx.x & 63;
  float4 xv = *(const float4*)(x + (size_t)row*FD + l*4);
  float4 ws = *(const float4*)(w_src + l*4);
  float4 wd = *(const float4*)(w_dst + l*4);
  float s = dot4(xv, ws);
  float d = dot4(xv, wd);
#pragma unroll
  for (int m=1;m<64;m<<=1){ s += __shfl_xor(s, m); d += __shfl_xor(d, m); }
  if (l == 0){ e_src[row] = s; e_dst[row] = d; }
  uint2 u;
  u.x = (unsigned)f2bf(xv.x) | ((unsigned)f2bf(xv.y)<<16);
  u.y = (unsigned)f2bf(xv.z) | ((unsigned)f2bf(xv.w)<<16);
  *(uint2*)(xb + (size_t)row*FD + l*4) = u;
}

// ---------------------------------------------------------------------------
// K1: h = x @ W in bf16 MFMA (16x16x32), fp32 accum, written TRANSPOSED:
//     hT[b][o][n]  so the fused kernel's B-fragments are contiguous along n(=m).
// One wave per 16 rows. A from xb (global, 16B loads), B from WT (L1/L2-hot).
// ---------------------------------------------------------------------------
__global__ __launch_bounds__(64,1) void gemm_h(
    const unsigned short* __restrict__ xb,
    const unsigned short* __restrict__ WT,
    unsigned short* __restrict__ hT)
{
  const int wid = blockIdx.x;          // 1024 tiles of 16 rows
  const int l = threadIdx.x;
  const int r16 = l & 15, g = l >> 4;
  const int row0 = wid << 4;

  f32x4 acc[16];
#pragma unroll
  for (int c=0;c<16;c++) acc[c] = (f32x4){0.f,0.f,0.f,0.f};

  const unsigned short* xrow = xb + (size_t)(row0 + r16)*FD + g*8;
#pragma unroll
  for (int s=0;s<8;s++){
    int4 av = *(const int4*)(xrow + s*32);
    short8 afrag = __builtin_bit_cast(short8, av);
#pragma unroll
    for (int c=0;c<16;c++){
      int4 bv = *(const int4*)(WT + (c*16 + r16)*FD + s*32 + g*8);
      acc[c] = __builtin_amdgcn_mfma_f32_16x16x32_bf16(
                 afrag, __builtin_bit_cast(short8, bv), acc[c], 0, 0, 0);
    }
  }
  // C frag: col = l&15, row = g*4 + r.  Write hT[b][o][n], 4 consecutive n packed.
  const int b  = row0 >> 11;           // 2048 rows per batch
  const int nb = (row0 + g*4) & (NN-1);
  unsigned short* hTB = hT + (size_t)b*FD*NN;
#pragma unroll
  for (int c=0;c<16;c++){
    const int o = c*16 + r16;
    uint2 u;
    u.x = (unsigned)f2bf(acc[c][0]) | ((unsigned)f2bf(acc[c][1])<<16);
    u.y = (unsigned)f2bf(acc[c][2]) | ((unsigned)f2bf(acc[c][3])<<16);
    *(uint2*)(hTB + (size_t)o*NN + nb) = u;
  }
}

// ---------------------------------------------------------------------------
// K2: fused scores + (no-max) exp + PV + normalize + ELU.
// One wave per 16 output rows; m-loop in steps of 32.
//   P[n][m] = adj ? exp(leaky(e_src[n]+e_dst[m])) : 0   (unnormalized, fp32->bf16)
//   O += P @ H   via 16 MFMA/step;  final O[row]/rowsum, ELU.
// adj+e_dst prefetched 2 steps ahead (HBM latency), B-frags 1 step ahead (L2).
// ---------------------------------------------------------------------------
__global__ __launch_bounds__(64,1) void gat_fused(
    const int* __restrict__ adj,
    const float* __restrict__ e_src,
    const float* __restrict__ e_dst,
    const unsigned short* __restrict__ hT,
    float* __restrict__ out)
{
  const int wid = blockIdx.x;          // 8 b * 128 n-tiles
  const int b  = wid >> 7;
  const int nt = wid & 127;
  const int n0 = nt << 4;
  const int l  = threadIdx.x;
  const int r16 = l & 15;
  const int g   = l >> 4;

  // A-frag lane mapping: row = l&15, k(=m within step) = g*8 + j
  const int* adjR = adj + ((size_t)b*NN + n0 + r16)*NN + g*8;
  const float* edB = e_dst + b*NN + g*8;
  const unsigned short* hTB = hT + (size_t)b*FD*NN + (size_t)r16*NN + g*8;
  const float es = e_src[b*NN + n0 + r16];

  f32x4 acc[16];
#pragma unroll
  for (int c=0;c<16;c++) acc[c] = (f32x4){0.f,0.f,0.f,0.f};
  float ps = 0.f;

  int4 aj00,aj01,aj10,aj11;
  float4 ed00,ed01,ed10,ed11;
  int4 bfA[16], bfB[16];

  auto load_pf = [&](int4& a0, int4& a1, float4& e0, float4& e1, int m){
    const int* ap = adjR + m*32;
    a0 = *(const int4*)ap;
    a1 = *(const int4*)(ap+4);
    const float* ep = edB + m*32;
    e0 = *(const float4*)ep;
    e1 = *(const float4*)(ep+4);
  };
  auto load_b = [&](int4* bf, int m){
#pragma unroll
    for (int c=0;c<16;c++)
      bf[c] = *(const int4*)(hTB + (size_t)c*16*NN + m*32);
  };
  auto mkp = [&](int4 a0, int4 a1, float4 e0, float4 e1)->short8{
    int   ai[8] = {a0.x,a0.y,a0.z,a0.w,a1.x,a1.y,a1.z,a1.w};
    float ev[8] = {e0.x,e0.y,e0.z,e0.w,e1.x,e1.y,e1.z,e1.w};
    union { short8 v; unsigned short u[8]; } A;
#pragma unroll
    for (int j=0;j<8;j++){
      float s = es + ev[j];
      s = s > 0.f ? s : ALPHA*s;              // leaky relu
      float p = (ai[j] > 0) ? __expf(s) : 0.f; // mask -> exact 0
      unsigned short pb = f2bf(p);
      A.u[j] = pb;
      ps += bf2f(pb);                          // rowsum of the ROUNDED P
    }
    return A.v;
  };
  auto domfma = [&](int4* bf, short8 pa){
#pragma unroll
    for (int c=0;c<16;c++)
      acc[c] = __builtin_amdgcn_mfma_f32_16x16x32_bf16(
                 pa, __builtin_bit_cast(short8, bf[c]), acc[c], 0, 0, 0);
  };

  load_pf(aj00,aj01,ed00,ed01, 0);
  load_pf(aj10,aj11,ed10,ed11, 1);
  load_b(bfA, 0);

  for (int t=0; t<64; t+=2){
    const int t2 = (t+2 < 64) ? t+2 : 0;     // clamped dummy prefetch at tail
    const int t3 = (t+3 < 64) ? t+3 : 0;
    load_b(bfB, t+1);
    short8 pa0 = mkp(aj00,aj01,ed00,ed01);
    load_pf(aj00,aj01,ed00,ed01, t2);
    domfma(bfA, pa0);
    load_b(bfA, t2);
    short8 pa1 = mkp(aj10,aj11,ed10,ed11);
    load_pf(aj10,aj11,ed10,ed11, t3);
    domfma(bfB, pa1);
  }

  // rowsum: lane holds partial for row r16; reduce across the 4 k-groups
  float rs = ps;
  rs += __shfl_xor(rs, 16);
  rs += __shfl_xor(rs, 32);

  float inv[4];
#pragma unroll
  for (int r=0;r<4;r++){
    float rr = __shfl(rs, g*4 + r);          // full sum for C-frag row g*4+r
    inv[r] = 1.0f / rr;
  }
  float* outB = out + ((size_t)b*NN + n0)*FD;
#pragma unroll
  for (int c=0;c<16;c++){
#pragma unroll
    for (int r=0;r<4;r++){
      float v = acc[c][r] * inv[r];
      v = v > 0.f ? v : (__expf(v) - 1.f);   // ELU
      outB[(size_t)(g*4 + r)*FD + c*16 + r16] = v;
    }
  }
}

// ---------------------------------------------------------------------------
extern "C" void kernel_launch(void* const* d_in, const int* in_sizes, int n_in,
                              void* d_out, int out_size, void* d_ws, size_t ws_size,
                              hipStream_t stream)
{
  const float* x   = (const float*)d_in[0];
  const int*   adj = (const int*)  d_in[1];
  const float* W   = (const float*)d_in[2];
  const float* a   = (const float*)d_in[3];
  float* out = (float*)d_out;

  char* ws = (char*)d_ws;
  size_t off = 0;
  auto alloc = [&](size_t bytes)->char*{
    char* p = ws + off; off += (bytes + 255) & ~(size_t)255; return p;
  };
  unsigned short* WT    = (unsigned short*)alloc((size_t)FD*FD*2);     // 128 KB
  float*          w_src = (float*)alloc(FD*4);
  float*          w_dst = (float*)alloc(FD*4);
  float*          e_src = (float*)alloc((size_t)BATCH*NN*4);           // 64 KB
  float*          e_dst = (float*)alloc((size_t)BATCH*NN*4);
  unsigned short* xb    = (unsigned short*)alloc((size_t)BATCH*NN*FD*2); // 8.4 MB
  unsigned short* hT    = (unsigned short*)alloc((size_t)BATCH*NN*FD*2); // 8.4 MB

  prep_w   <<<FD,              64,  0, stream>>>(W, a, w_src, w_dst, WT);
  prep_x   <<<(BATCH*NN)/4,    256, 0, stream>>>(x, w_src, w_dst, xb, e_src, e_dst);
  gemm_h   <<<(BATCH*NN)/16,   64,  0, stream>>>(xb, WT, hT);
  gat_fused<<<(BATCH*NN)/16,   64,  0, stream>>>(adj, e_src, e_dst, hT, out);
}

// Round 2
// 196.914 us; speedup vs baseline: 1.0168x; 1.0168x over previous
//
#include <hip/hip_runtime.h>

#define ALPHA 0.2f
#define BATCH 8
#define NN    2048
#define FD    256

typedef __attribute__((ext_vector_type(8))) short short8;
typedef __attribute__((ext_vector_type(4))) float f32x4;

__device__ __forceinline__ unsigned short f2bf(float f){
  unsigned u = __builtin_bit_cast(unsigned, f);
  return (unsigned short)((u + 0x7FFFu + ((u>>16)&1u)) >> 16);   // RTN-even
}
__device__ __forceinline__ float dot4(float4 a, float4 b){
  return a.x*b.x + a.y*b.y + a.z*b.z + a.w*b.w;
}

// ---------------------------------------------------------------------------
// K0: w_src = W @ a_src, w_dst = W @ a_dst (exact fp32), WT[o][k] = bf16(W[k][o])
// ---------------------------------------------------------------------------
__global__ __launch_bounds__(64) void prep_w(
    const float* __restrict__ W, const float* __restrict__ a,
    float* __restrict__ w_src, float* __restrict__ w_dst,
    unsigned short* __restrict__ WT)
{
  const int k = blockIdx.x;
  const int l = threadIdx.x;
  float4 wv = *(const float4*)(W + k*FD + l*4);
  float4 as = *(const float4*)(a + l*4);
  float4 ad = *(const float4*)(a + FD + l*4);
  float s = dot4(wv, as);
  float d = dot4(wv, ad);
#pragma unroll
  for (int m=1;m<64;m<<=1){ s += __shfl_xor(s, m); d += __shfl_xor(d, m); }
  if (l == 0){ w_src[k] = s; w_dst[k] = d; }
  WT[(l*4+0)*FD + k] = f2bf(wv.x);
  WT[(l*4+1)*FD + k] = f2bf(wv.y);
  WT[(l*4+2)*FD + k] = f2bf(wv.z);
  WT[(l*4+3)*FD + k] = f2bf(wv.w);
}

// ---------------------------------------------------------------------------
// K0b: e_src/e_dst fp32 per row; xb = bf16(x)
// ---------------------------------------------------------------------------
__global__ __launch_bounds__(256) void prep_x(
    const float* __restrict__ x,
    const float* __restrict__ w_src, const float* __restrict__ w_dst,
    unsigned short* __restrict__ xb,
    float* __restrict__ e_src, float* __restrict__ e_dst)
{
  const int row = blockIdx.x*4 + (threadIdx.x >> 6);
  const int l = threadIdx.x & 63;
  float4 xv = *(const float4*)(x + (size_t)row*FD + l*4);
  float4 ws = *(const float4*)(w_src + l*4);
  float4 wd = *(const float4*)(w_dst + l*4);
  float s = dot4(xv, ws);
  float d = dot4(xv, wd);
#pragma unroll
  for (int m=1;m<64;m<<=1){ s += __shfl_xor(s, m); d += __shfl_xor(d, m); }
  if (l == 0){ e_src[row] = s; e_dst[row] = d; }
  uint2 u;
  u.x = (unsigned)f2bf(xv.x) | ((unsigned)f2bf(xv.y)<<16);
  u.y = (unsigned)f2bf(xv.z) | ((unsigned)f2bf(xv.w)<<16);
  *(uint2*)(xb + (size_t)row*FD + l*4) = u;
}

// ---------------------------------------------------------------------------
// K1: h = x @ W, bf16 MFMA, output transposed hT[b][o][n].
// 4 waves/block, c-split: wave w owns output cols [64w, 64w+64).
// ---------------------------------------------------------------------------
__global__ __launch_bounds__(256) void gemm_h(
    const unsigned short* __restrict__ xb,
    const unsigned short* __restrict__ WT,
    unsigned short* __restrict__ hT)
{
  const int tid = threadIdx.x;
  const int w = tid >> 6, l = tid & 63;
  const int r16 = l & 15, g = l >> 4;
  const int row0 = blockIdx.x << 4;

  f32x4 acc[4];
#pragma unroll
  for (int c=0;c<4;c++) acc[c] = (f32x4){0.f,0.f,0.f,0.f};

  const unsigned short* xrow  = xb + (size_t)(row0 + r16)*FD + g*8;
  const unsigned short* wbase = WT + (size_t)(w*64 + r16)*FD + g*8;
#pragma unroll
  for (int s=0;s<8;s++){
    short8 afrag = __builtin_bit_cast(short8, *(const int4*)(xrow + s*32));
#pragma unroll
    for (int cl=0;cl<4;cl++){
      int4 bv = *(const int4*)(wbase + (size_t)cl*16*FD + s*32);
      acc[cl] = __builtin_amdgcn_mfma_f32_16x16x32_bf16(
                  afrag, __builtin_bit_cast(short8, bv), acc[cl], 0, 0, 0);
    }
  }
  const int b  = row0 >> 11;
  const int nb = (row0 + g*4) & (NN-1);
  unsigned short* hTB = hT + (size_t)b*FD*NN;
#pragma unroll
  for (int cl=0;cl<4;cl++){
    const int o = w*64 + cl*16 + r16;
    uint2 u;
    u.x = (unsigned)f2bf(acc[cl][0]) | ((unsigned)f2bf(acc[cl][1])<<16);
    u.y = (unsigned)f2bf(acc[cl][2]) | ((unsigned)f2bf(acc[cl][3])<<16);
    *(uint2*)(hTB + (size_t)o*NN + nb) = u;
  }
}

// ---------------------------------------------------------------------------
// K2: fused scores + exp + PV + normalize + ELU.
// 4 waves/block, m-split: wave w handles m in [512w, 512w+512) (16 steps of 32).
// Partial accumulators combined via LDS (2 rounds of 8 c-blocks, 32 KB).
// ---------------------------------------------------------------------------
__global__ __launch_bounds__(256) void gat_fused(
    const int* __restrict__ adj,
    const float* __restrict__ e_src,
    const float* __restrict__ e_dst,
    const unsigned short* __restrict__ hT,
    float* __restrict__ out)
{
  __shared__ f32x4 red[8][4][64];                 // 32 KB
  __shared__ __align__(16) float rsum[4][16];

  const int tid = threadIdx.x;
  const int w = tid >> 6;
  const int l = tid & 63;
  const int r16 = l & 15, g = l >> 4;
  const int wid = blockIdx.x;
  const int b  = wid >> 7;
  const int n0 = (wid & 127) << 4;
  const int mb = w << 9;                          // wave's m-chunk base

  const int* adjR = adj + ((size_t)b*NN + n0 + r16)*NN + mb + g*8;
  const float* edB = e_dst + b*NN + mb + g*8;
  const unsigned short* hTB = hT + (size_t)b*FD*NN + (size_t)r16*NN + mb + g*8;
  const float es = e_src[b*NN + n0 + r16];

  f32x4 acc[16];
#pragma unroll
  for (int c=0;c<16;c++) acc[c] = (f32x4){0.f,0.f,0.f,0.f};
  float ps = 0.f;

  int4 ajA0,ajA1,ajB0,ajB1;
  float4 edA0,edA1,edB0,edB1;
  int4 bh0[8], bh1[8];

  auto load_pf = [&](int4& a0,int4& a1,float4& e0,float4& e1,int t){
    const int* ap = adjR + t*32;
    a0 = *(const int4*)ap; a1 = *(const int4*)(ap+4);
    const float* ep = edB + t*32;
    e0 = *(const float4*)ep; e1 = *(const float4*)(ep+4);
  };
  auto load_h = [&](int4* bf, int t, int half){
#pragma unroll
    for (int c=0;c<8;c++)
      bf[c] = *(const int4*)(hTB + (size_t)(half*8+c)*16*NN + t*32);
  };
  // P-frag: exp(leaky(es+ed)) masked, truncated to bf16; ps sums the TRUNCATED
  // values so numerator/denominator rounding bias cancels.
  auto mkp = [&](int4 a0,int4 a1,float4 e0,float4 e1)->short8{
    int   ai[8] = {a0.x,a0.y,a0.z,a0.w,a1.x,a1.y,a1.z,a1.w};
    float ev[8] = {e0.x,e0.y,e0.z,e0.w,e1.x,e1.y,e1.z,e1.w};
    unsigned pt[8];
#pragma unroll
    for (int j=0;j<8;j++){
      float s = es + ev[j];
      s = fmaxf(s, ALPHA*s);                       // leaky relu
      float p = __expf(s);
      p = (ai[j] > 0) ? p : 0.f;
      unsigned ub = __builtin_bit_cast(unsigned, p) & 0xFFFF0000u;
      ps += __builtin_bit_cast(float, ub);
      pt[j] = ub;
    }
    union { short8 v; unsigned u[4]; } A;
#pragma unroll
    for (int j=0;j<4;j++) A.u[j] = pt[2*j+1] | (pt[2*j] >> 16);
    return A.v;
  };
  auto mfma_h = [&](int4* bf, short8 pa, int half){
#pragma unroll
    for (int c=0;c<8;c++)
      acc[half*8+c] = __builtin_amdgcn_mfma_f32_16x16x32_bf16(
          pa, __builtin_bit_cast(short8, bf[c]), acc[half*8+c], 0, 0, 0);
  };

  load_pf(ajA0,ajA1,edA0,edA1, 0);
  load_pf(ajB0,ajB1,edB0,edB1, 1);
  load_h(bh0, 0, 0);

  for (int t=0; t<16; t+=2){
    const int tA = (t+2<16)? t+2 : 0;
    const int tB = (t+3<16)? t+3 : 0;
    // step t
    load_h(bh1, t, 1);
    short8 pa0 = mkp(ajA0,ajA1,edA0,edA1);
    load_pf(ajA0,ajA1,edA0,edA1, tA);
    mfma_h(bh0, pa0, 0);
    load_h(bh0, t+1, 0);
    mfma_h(bh1, pa0, 1);
    // step t+1
    load_h(bh1, t+1, 1);
    short8 pa1 = mkp(ajB0,ajB1,edB0,edB1);
    load_pf(ajB0,ajB1,edB0,edB1, tB);
    mfma_h(bh0, pa1, 0);
    load_h(bh0, tA, 0);
    mfma_h(bh1, pa1, 1);
  }

  // ---- rowsum partial: every lane ends with wave-total for row r16 ----
  float rs = ps;
  rs += __shfl_xor(rs, 16);
  rs += __shfl_xor(rs, 32);
  if (l < 16) rsum[w][l] = rs;

  // ---- stage acc c in [0,8) ----
#pragma unroll
  for (int c=0;c<8;c++) red[c][w][l] = acc[c];
  __syncthreads();

  // row totals for this lane's 4 rows (g*4 + r)
  f32x4 rt0 = *(const f32x4*)&rsum[0][g*4];
  f32x4 rt1 = *(const f32x4*)&rsum[1][g*4];
  f32x4 rt2 = *(const f32x4*)&rsum[2][g*4];
  f32x4 rt3 = *(const f32x4*)&rsum[3][g*4];
  f32x4 rt = rt0 + rt1 + rt2 + rt3;
  f32x4 inv;
#pragma unroll
  for (int r=0;r<4;r++) inv[r] = 1.0f / rt[r];

  float* outB = out + ((size_t)b*NN + n0)*FD;

  // ---- reduce round 0: wave w finalizes c = 2w, 2w+1 ----
#pragma unroll
  for (int i=0;i<2;i++){
    const int c = 2*w + i;
    f32x4 v = red[c][0][l] + red[c][1][l] + red[c][2][l] + red[c][3][l];
#pragma unroll
    for (int r=0;r<4;r++){
      float o = v[r] * inv[r];
      o = o > 0.f ? o : (__expf(o) - 1.f);         // ELU
      outB[(size_t)(g*4 + r)*FD + c*16 + r16] = o;
    }
  }
  __syncthreads();

  // ---- stage acc c in [8,16) ----
#pragma unroll
  for (int c=0;c<8;c++) red[c][w][l] = acc[8+c];
  __syncthreads();

  // ---- reduce round 1: c_out = 8 + 2w + i ----
#pragma unroll
  for (int i=0;i<2;i++){
    const int cl = 2*w + i;
    const int c  = 8 + cl;
    f32x4 v = red[cl][0][l] + red[cl][1][l] + red[cl][2][l] + red[cl][3][l];
#pragma unroll
    for (int r=0;r<4;r++){
      float o = v[r] * inv[r];
      o = o > 0.f ? o : (__expf(o) - 1.f);
      outB[(size_t)(g*4 + r)*FD + c*16 + r16] = o;
    }
  }
}

// ---------------------------------------------------------------------------
extern "C" void kernel_launch(void* const* d_in, const int* in_sizes, int n_in,
                              void* d_out, int out_size, void* d_ws, size_t ws_size,
                              hipStream_t stream)
{
  const float* x   = (const float*)d_in[0];
  const int*   adj = (const int*)  d_in[1];
  const float* W   = (const float*)d_in[2];
  const float* a   = (const float*)d_in[3];
  float* out = (float*)d_out;

  char* ws = (char*)d_ws;
  size_t off = 0;
  auto alloc = [&](size_t bytes)->char*{
    char* p = ws + off; off += (bytes + 255) & ~(size_t)255; return p;
  };
  unsigned short* WT    = (unsigned short*)alloc((size_t)FD*FD*2);
  float*          w_src = (float*)alloc(FD*4);
  float*          w_dst = (float*)alloc(FD*4);
  float*          e_src = (float*)alloc((size_t)BATCH*NN*4);
  float*          e_dst = (float*)alloc((size_t)BATCH*NN*4);
  unsigned short* xb    = (unsigned short*)alloc((size_t)BATCH*NN*FD*2);
  unsigned short* hT    = (unsigned short*)alloc((size_t)BATCH*NN*FD*2);

  prep_w   <<<FD,              64,  0, stream>>>(W, a, w_src, w_dst, WT);
  prep_x   <<<(BATCH*NN)/4,    256, 0, stream>>>(x, w_src, w_dst, xb, e_src, e_dst);
  gemm_h   <<<(BATCH*NN)/16,   256, 0, stream>>>(xb, WT, hT);
  gat_fused<<<(BATCH*NN)/16,   256, 0, stream>>>(adj, e_src, e_dst, hT, out);
}

// Round 3
// 110.368 us; speedup vs baseline: 1.8141x; 1.7842x over previous
//
#include <hip/hip_runtime.h>

#define ALPHA 0.2f
#define BATCH 8
#define NN    2048
#define FD    256
#define NT    64          // m-steps of 32
#define TILEB 16384       // one hT tile: 256 o x 32 m x 2B

typedef __attribute__((ext_vector_type(8))) short short8;
typedef __attribute__((ext_vector_type(4))) float f32x4;

__device__ __forceinline__ unsigned short f2bf(float f){
  unsigned u = __builtin_bit_cast(unsigned, f);
  return (unsigned short)((u + 0x7FFFu + ((u>>16)&1u)) >> 16);   // RTN-even
}
__device__ __forceinline__ float dot4(float4 a, float4 b){
  return a.x*b.x + a.y*b.y + a.z*b.z + a.w*b.w;
}
// async global->LDS, 16B per lane. dest = lds base (wave-uniform) + lane*16.
__device__ __forceinline__ void gll16(const void* g, void* l){
  __builtin_amdgcn_global_load_lds(
      (const __attribute__((address_space(1))) unsigned int*)g,
      (__attribute__((address_space(3))) unsigned int*)l, 16, 0, 0);
}

// ---------------------------------------------------------------------------
// K0: w_src = W @ a_src, w_dst = W @ a_dst (exact fp32), WT[o][k] = bf16(W[k][o])
// ---------------------------------------------------------------------------
__global__ __launch_bounds__(64) void prep_w(
    const float* __restrict__ W, const float* __restrict__ a,
    float* __restrict__ w_src, float* __restrict__ w_dst,
    unsigned short* __restrict__ WT)
{
  const int k = blockIdx.x;
  const int l = threadIdx.x;
  float4 wv = *(const float4*)(W + k*FD + l*4);
  float4 as = *(const float4*)(a + l*4);
  float4 ad = *(const float4*)(a + FD + l*4);
  float s = dot4(wv, as);
  float d = dot4(wv, ad);
#pragma unroll
  for (int m=1;m<64;m<<=1){ s += __shfl_xor(s, m); d += __shfl_xor(d, m); }
  if (l == 0){ w_src[k] = s; w_dst[k] = d; }
  WT[(l*4+0)*FD + k] = f2bf(wv.x);
  WT[(l*4+1)*FD + k] = f2bf(wv.y);
  WT[(l*4+2)*FD + k] = f2bf(wv.z);
  WT[(l*4+3)*FD + k] = f2bf(wv.w);
}

// ---------------------------------------------------------------------------
// K0b: e_src/e_dst fp32 per row; xb = bf16(x)
// ---------------------------------------------------------------------------
__global__ __launch_bounds__(256) void prep_x(
    const float* __restrict__ x,
    const float* __restrict__ w_src, const float* __restrict__ w_dst,
    unsigned short* __restrict__ xb,
    float* __restrict__ e_src, float* __restrict__ e_dst)
{
  const int row = blockIdx.x*4 + (threadIdx.x >> 6);
  const int l = threadIdx.x & 63;
  float4 xv = *(const float4*)(x + (size_t)row*FD + l*4);
  float4 ws = *(const float4*)(w_src + l*4);
  float4 wd = *(const float4*)(w_dst + l*4);
  float s = dot4(xv, ws);
  float d = dot4(xv, wd);
#pragma unroll
  for (int m=1;m<64;m<<=1){ s += __shfl_xor(s, m); d += __shfl_xor(d, m); }
  if (l == 0){ e_src[row] = s; e_dst[row] = d; }
  uint2 u;
  u.x = (unsigned)f2bf(xv.x) | ((unsigned)f2bf(xv.y)<<16);
  u.y = (unsigned)f2bf(xv.z) | ((unsigned)f2bf(xv.w)<<16);
  *(uint2*)(xb + (size_t)row*FD + l*4) = u;
}

// ---------------------------------------------------------------------------
// K1: h = x @ W, bf16 MFMA, output transposed hT[b][o][n].
// 4 waves/block, c-split: wave w owns output cols [64w, 64w+64).
// ---------------------------------------------------------------------------
__global__ __launch_bounds__(256) void gemm_h(
    const unsigned short* __restrict__ xb,
    const unsigned short* __restrict__ WT,
    unsigned short* __restrict__ hT)
{
  const int tid = threadIdx.x;
  const int w = tid >> 6, l = tid & 63;
  const int r16 = l & 15, g = l >> 4;
  const int row0 = blockIdx.x << 4;

  f32x4 acc[4];
#pragma unroll
  for (int c=0;c<4;c++) acc[c] = (f32x4){0.f,0.f,0.f,0.f};

  const unsigned short* xrow  = xb + (size_t)(row0 + r16)*FD + g*8;
  const unsigned short* wbase = WT + (size_t)(w*64 + r16)*FD + g*8;
#pragma unroll
  for (int s=0;s<8;s++){
    short8 afrag = __builtin_bit_cast(short8, *(const int4*)(xrow + s*32));
#pragma unroll
    for (int cl=0;cl<4;cl++){
      int4 bv = *(const int4*)(wbase + (size_t)cl*16*FD + s*32);
      acc[cl] = __builtin_amdgcn_mfma_f32_16x16x32_bf16(
                  afrag, __builtin_bit_cast(short8, bv), acc[cl], 0, 0, 0);
    }
  }
  const int b  = row0 >> 11;
  const int nb = (row0 + g*4) & (NN-1);
  unsigned short* hTB = hT + (size_t)b*FD*NN;
#pragma unroll
  for (int cl=0;cl<4;cl++){
    const int o = w*64 + cl*16 + r16;
    uint2 u;
    u.x = (unsigned)f2bf(acc[cl][0]) | ((unsigned)f2bf(acc[cl][1])<<16);
    u.y = (unsigned)f2bf(acc[cl][2]) | ((unsigned)f2bf(acc[cl][3])<<16);
    *(uint2*)(hTB + (size_t)o*NN + nb) = u;
  }
}

// ---------------------------------------------------------------------------
// K2: fused scores + exp + PV + normalize + ELU.
// Grid 256 = 8 XCD-batches x 32 n-tiles of 64 rows. 4 waves/block, n-split:
// wave wv owns rows n0+16*wv..+16, full m range. hT tile (16 KB/step) staged
// in LDS (triple-buffered, depth-2 prefetch, counted vmcnt); adj/e_dst
// register-prefetched. XOR-swizzled LDS (bits 4-5 by (o>>1)&3) for
// conflict-free ds_read_b128; source pre-swizzled for linear gll writes.
// ---------------------------------------------------------------------------
__global__ __launch_bounds__(256,1) void gat_fused(
    const int* __restrict__ adj,
    const float* __restrict__ e_src,
    const float* __restrict__ e_dst,
    const unsigned short* __restrict__ hT,
    float* __restrict__ out)
{
  __shared__ __align__(16) char smem[3*TILEB];

  const int tid = threadIdx.x;
  const int wv  = tid >> 6;            // wave id = n-sub-tile
  const int l   = tid & 63;
  const int r16 = l & 15, g = l >> 4;
  const int b   = blockIdx.x & 7;      // XCD-affine batch
  const int n0  = (blockIdx.x >> 3) << 6;

  const int* adjR = adj + (size_t)(b*NN + n0 + wv*16 + r16)*NN + g*8;
  const float* edB = e_dst + b*NN + g*8;
  const unsigned short* hTb = hT + (size_t)b*FD*NN;
  const float es = e_src[b*NN + n0 + wv*16 + r16];

  // --- staging source precompute: linear LDS dest -> inverse-swizzled src ---
  const unsigned short* hsrc[4];
#pragma unroll
  for (int i=0;i<4;i++){
    int dl  = wv*4096 + i*1024 + l*16;            // linear dest byte
    int ds_ = dl ^ (((dl>>7)&3)<<4);              // involution on bits 4-5
    int o   = ds_ >> 6;
    int mq  = (ds_ >> 4) & 3;
    hsrc[i] = hTb + (size_t)o*NN + mq*8;          // + m0 per step
  }
  // B-frag read offset (swizzled): o = c*16+r16, k-group g
  const int hoff = (r16*64 + g*16) ^ (((r16>>1)&3)<<4);

  f32x4 acc[16];
#pragma unroll
  for (int c=0;c<16;c++) acc[c] = (f32x4){0.f,0.f,0.f,0.f};
  float ps = 0.f;

  int4 ajA0,ajA1,ajB0,ajB1;
  float4 eA0,eA1,eB0,eB1;

  auto mkp = [&](int4 a0,int4 a1,float4 e0,float4 e1)->short8{
    int   ai[8] = {a0.x,a0.y,a0.z,a0.w,a1.x,a1.y,a1.z,a1.w};
    float ev[8] = {e0.x,e0.y,e0.z,e0.w,e1.x,e1.y,e1.z,e1.w};
    unsigned pt[8];
#pragma unroll
    for (int j=0;j<8;j++){
      float s = es + ev[j];
      s = fmaxf(s, ALPHA*s);                       // leaky relu
      float p = __expf(s);
      p = (ai[j] > 0) ? p : 0.f;
      unsigned ub = __builtin_bit_cast(unsigned, p) & 0xFFFF0000u;
      ps += __builtin_bit_cast(float, ub);         // rowsum of truncated P
      pt[j] = ub;
    }
    union { short8 v; unsigned u[4]; } A;
#pragma unroll
    for (int j=0;j<4;j++) A.u[j] = pt[2*j+1] | (pt[2*j] >> 16);
    return A.v;
  };

  // ---- prologue: e(0), adj(0), adj(1), stage(0), stage(1) ----
  { const float* p = edB;      eA0 = *(const float4*)p; eA1 = *(const float4*)(p+4); }
  { const int* p = adjR;       ajA0 = *(const int4*)p;  ajA1 = *(const int4*)(p+4); }
  { const int* p = adjR + 32;  ajB0 = *(const int4*)p;  ajB1 = *(const int4*)(p+4); }
#pragma unroll
  for (int i=0;i<4;i++) gll16(hsrc[i],      smem +         wv*4096 + i*1024);
  __builtin_amdgcn_sched_barrier(0);
#pragma unroll
  for (int i=0;i<4;i++) gll16(hsrc[i] + 32, smem + TILEB + wv*4096 + i*1024);
  __builtin_amdgcn_sched_barrier(0);
  asm volatile("s_waitcnt vmcnt(4) lgkmcnt(0)" ::: "memory");
  __builtin_amdgcn_s_barrier();
  __builtin_amdgcn_sched_barrier(0);

  // per-step body.  vm issue order: e(2) aj(2) gll(4) = 8 ops -> vmcnt(8)
  auto STEP = [&](int tt, int rdo, int sto,
                  float4& ec0, float4& ec1, float4& en0, float4& en1,
                  int4& a0, int4& a1){
    { const float* p = edB + ((tt+1)&63)*32;       // e for tt+1
      en0 = *(const float4*)p; en1 = *(const float4*)(p+4); }
    short8 pa = mkp(a0,a1,ec0,ec1);                // consume slot, then refill
    { const int* p = adjR + ((tt+2)&63)*32;        // adj for tt+2
      a0 = *(const int4*)p; a1 = *(const int4*)(p+4); }
    { int ms = ((tt+2)&63)*32;                     // stage tile tt+2
#pragma unroll
      for (int i=0;i<4;i++) gll16(hsrc[i] + ms, smem + sto + wv*4096 + i*1024);
    }
    const char* hb = smem + rdo;
#pragma unroll
    for (int c=0;c<16;c++){
      int4 bv = *(const int4*)(hb + hoff + c*1024);
      acc[c] = __builtin_amdgcn_mfma_f32_16x16x32_bf16(
                 pa, __builtin_bit_cast(short8, bv), acc[c], 0, 0, 0);
    }
    __builtin_amdgcn_sched_barrier(0);
    asm volatile("s_waitcnt vmcnt(8) lgkmcnt(0)" ::: "memory");
    __builtin_amdgcn_s_barrier();
    __builtin_amdgcn_sched_barrier(0);
  };

  int cur = 0;
  for (int it = 0; it < 32; ++it){
    const int t0 = it*2;
    STEP(t0,   cur*TILEB, ((cur+2)%3)*TILEB, eA0,eA1, eB0,eB1, ajA0,ajA1);
    cur = (cur+1)%3;
    STEP(t0+1, cur*TILEB, ((cur+2)%3)*TILEB, eB0,eB1, eA0,eA1, ajB0,ajB1);
    cur = (cur+1)%3;
  }
  // keep tail dummy loads alive so per-step vm op counts stay exact (vmcnt!)
  asm volatile("" :: "v"(ajA0.x),"v"(ajA1.x),"v"(ajB0.x),"v"(ajB1.x),
                     "v"(eA0.x),"v"(eA1.x));

  // ---- epilogue: rowsum, normalize, ELU, store ----
  float rs = ps;
  rs += __shfl_xor(rs, 16);
  rs += __shfl_xor(rs, 32);
  float inv_[4];
#pragma unroll
  for (int r=0;r<4;r++) inv_[r] = 1.0f / __shfl(rs, g*4 + r);

  float* outB = out + (size_t)(b*NN + n0 + wv*16)*FD;
#pragma unroll
  for (int c=0;c<16;c++){
#pragma unroll
    for (int r=0;r<4;r++){
      float v = acc[c][r] * inv_[r];
      v = v > 0.f ? v : (__expf(v) - 1.f);         // ELU
      outB[(size_t)(g*4 + r)*FD + c*16 + r16] = v;
    }
  }
}

// ---------------------------------------------------------------------------
extern "C" void kernel_launch(void* const* d_in, const int* in_sizes, int n_in,
                              void* d_out, int out_size, void* d_ws, size_t ws_size,
                              hipStream_t stream)
{
  const float* x   = (const float*)d_in[0];
  const int*   adj = (const int*)  d_in[1];
  const float* W   = (const float*)d_in[2];
  const float* a   = (const float*)d_in[3];
  float* out = (float*)d_out;

  char* ws = (char*)d_ws;
  size_t off = 0;
  auto alloc = [&](size_t bytes)->char*{
    char* p = ws + off; off += (bytes + 255) & ~(size_t)255; return p;
  };
  unsigned short* WT    = (unsigned short*)alloc((size_t)FD*FD*2);
  float*          w_src = (float*)alloc(FD*4);
  float*          w_dst = (float*)alloc(FD*4);
  float*          e_src = (float*)alloc((size_t)BATCH*NN*4);
  float*          e_dst = (float*)alloc((size_t)BATCH*NN*4);
  unsigned short* xb    = (unsigned short*)alloc((size_t)BATCH*NN*FD*2);
  unsigned short* hT    = (unsigned short*)alloc((size_t)BATCH*NN*FD*2);

  prep_w   <<<FD,              64,  0, stream>>>(W, a, w_src, w_dst, WT);
  prep_x   <<<(BATCH*NN)/4,    256, 0, stream>>>(x, w_src, w_dst, xb, e_src, e_dst);
  gemm_h   <<<(BATCH*NN)/16,   256, 0, stream>>>(xb, WT, hT);
  gat_fused<<<(BATCH*NN)/64,   256, 0, stream>>>(adj, e_src, e_dst, hT, out);
}